// Round 3
// baseline (328.601 us; speedup 1.0000x reference)
//
#include <hip/hip_runtime.h>
#include <hip/hip_bf16.h>
#include <math.h>

#define B_   8
#define C_   192
#define N_   3136
#define K_   9
#define OUT_ 384
#define G_   4
#define CG_  96   // in-channels per group (2C/G)
#define OG_  96   // out-channels per group

typedef __attribute__((ext_vector_type(8))) short short8;
typedef __attribute__((ext_vector_type(4))) float floatx4;

// ---------------- ws layout (bytes) ----------------
// xT : B*N*C   bf16 =  9,633,792
// xc : B*N*2C  bf16 = 19,267,584
// y  : B*OUT*N bf16 = 19,267,584
// st : OUT*2   f32
static const size_t OFF_XT = 0;
static const size_t OFF_XC = 9633792;
static const size_t OFF_Y  = OFF_XC + 19267584;
static const size_t OFF_ST = OFF_Y  + 19267584;

__device__ inline short f2bs(float f) {
    __hip_bfloat16 h = __float2bfloat16(f);
    union { __hip_bfloat16 h; short s; } u; u.h = h; return u.s;
}
__device__ inline float blo(unsigned int u) {
    unsigned int v = u << 16; return __builtin_bit_cast(float, v);
}
__device__ inline float bhi(unsigned int u) {
    unsigned int v = u & 0xffff0000u; return __builtin_bit_cast(float, v);
}
__device__ inline unsigned int packbf(float lo, float hi) {
    unsigned int l = (unsigned int)(unsigned short)f2bs(lo);
    unsigned int h = (unsigned int)(unsigned short)f2bs(hi);
    return (h << 16) | l;
}

// ---- Kernel A: transpose x [B,C,N] f32 -> xT [B,N,C] bf16; zero BN accum ----
__global__ __launch_bounds__(256) void k_transpose(const float* __restrict__ x,
                                                   __hip_bfloat16* __restrict__ xT,
                                                   float* __restrict__ st) {
    if (blockIdx.x == 0 && blockIdx.y == 0 && blockIdx.z == 0) {
        #pragma unroll
        for (int i = 0; i < 3; ++i) st[threadIdx.x + i * 256] = 0.0f;
    }
    __shared__ float tile[64][65];
    int b  = blockIdx.x;
    int cb = blockIdx.y * 64;
    int nb = blockIdx.z * 64;
    int tid = threadIdx.x;
    int tn  = tid & 63;
    int tc4 = tid >> 6;
    const float* xp = x + ((size_t)b * C_ + cb) * N_ + nb;
    #pragma unroll
    for (int i = 0; i < 16; ++i) {
        int c = tc4 + i * 4;
        tile[c][tn] = xp[(size_t)c * N_ + tn];
    }
    __syncthreads();
    __hip_bfloat16* xo = xT + ((size_t)b * N_ + nb) * C_ + cb;
    int tcl = tid & 63;
    int tn4 = tid >> 6;
    #pragma unroll
    for (int i = 0; i < 16; ++i) {
        int n = tn4 + i * 4;
        xo[(size_t)n * C_ + tcl] = __float2bfloat16(tile[tcl][n]);
    }
}

// ---- Kernel B: LEAN gather + max-relative -> xc [B,N,2C] bf16 ----
// 8 nodes per 256-block (one node per half-wave); dword loads; no LDS.
__global__ __launch_bounds__(256) void k_gather(const __hip_bfloat16* __restrict__ xT,
                                                const int* __restrict__ eidx,
                                                __hip_bfloat16* __restrict__ xc) {
    int b    = blockIdx.x;
    int tid  = threadIdx.x;
    int half = tid >> 5;              // 0..7: node slot within block
    int cd   = tid & 31;              // channel-dword lane
    int n    = blockIdx.y * 8 + half;

    const int* e0 = eidx + ((size_t)b * N_ + n) * K_;                        // x_j idx
    const int* e1 = eidx + (size_t)B_ * N_ * K_ + ((size_t)b * N_ + n) * K_; // x_i idx
    int o0[K_], o1[K_];
    #pragma unroll
    for (int k = 0; k < K_; ++k) { o0[k] = e0[k] * (C_ / 2); o1[k] = e1[k] * (C_ / 2); }

    const unsigned int* xb = reinterpret_cast<const unsigned int*>(xT + (size_t)b * N_ * C_);
    const unsigned int* xn = xb + (size_t)n * (C_ / 2);
    unsigned int* outrow = reinterpret_cast<unsigned int*>(xc) + ((size_t)b * N_ + n) * C_ * 2 / 2;

    #pragma unroll
    for (int it = 0; it < 3; ++it) {
        int c2 = cd + it * 32;        // dword idx in [0,96): channels 2c2, 2c2+1
        unsigned int ctr = xn[c2];
        float r0 = -INFINITY, r1 = -INFINITY;
        #pragma unroll
        for (int k = 0; k < K_; ++k) {
            unsigned int uj = xb[(size_t)o0[k] + c2];
            unsigned int ui = xb[(size_t)o1[k] + c2];
            r0 = fmaxf(r0, blo(uj) - blo(ui));
            r1 = fmaxf(r1, bhi(uj) - bhi(ui));
        }
        uint2 o;
        o.x = packbf(blo(ctr), r0);   // elems 4c2,4c2+1  : x_{2c2}, rel_{2c2}
        o.y = packbf(bhi(ctr), r1);   // elems 4c2+2,4c2+3: x_{2c2+1}, rel_{2c2+1}
        *reinterpret_cast<uint2*>(outrow + 2 * c2) = o;
    }
}

// ---- Kernel C: grouped 1x1 conv via bf16 MFMA + fused BN stats ----
__global__ __launch_bounds__(256) void k_conv(const __hip_bfloat16* __restrict__ xc,
                                              const float* __restrict__ conv_w,
                                              const float* __restrict__ bias,
                                              __hip_bfloat16* __restrict__ y,
                                              float* __restrict__ st) {
    int b  = blockIdx.x;
    int g  = blockIdx.y;
    int nt = blockIdx.z;
    int lane = threadIdx.x & 63;
    int wid  = threadIdx.x >> 6;
    int n0   = nt * 64 + wid * 16;
    int col  = lane & 15;
    int quad = lane >> 4;

    // weight fragments: fp32 -> bf16 in-register (L2-resident)
    short8 wf[3][6];
    #pragma unroll
    for (int mt = 0; mt < 6; ++mt) {
        #pragma unroll
        for (int kc = 0; kc < 3; ++kc) {
            const float* wp = conv_w + (size_t)(g * OG_ + mt * 16 + col) * CG_ + kc * 32 + quad * 8;
            float4 w0 = *reinterpret_cast<const float4*>(wp);
            float4 w1 = *reinterpret_cast<const float4*>(wp + 4);
            short8 v;
            v[0] = f2bs(w0.x); v[1] = f2bs(w0.y); v[2] = f2bs(w0.z); v[3] = f2bs(w0.w);
            v[4] = f2bs(w1.x); v[5] = f2bs(w1.y); v[6] = f2bs(w1.z); v[7] = f2bs(w1.w);
            wf[kc][mt] = v;
        }
    }

    const short* Xp = reinterpret_cast<const short*>(xc);
    size_t rowbase = ((size_t)b * N_ + n0 + col) * (2 * C_) + (size_t)g * CG_;
    short8 bfr[3];
    #pragma unroll
    for (int kc = 0; kc < 3; ++kc)
        bfr[kc] = *reinterpret_cast<const short8*>(Xp + rowbase + kc * 32 + quad * 8);

    floatx4 acc[6];
    #pragma unroll
    for (int mt = 0; mt < 6; ++mt) acc[mt] = (floatx4){0.f, 0.f, 0.f, 0.f};
    #pragma unroll
    for (int kc = 0; kc < 3; ++kc)
        #pragma unroll
        for (int mt = 0; mt < 6; ++mt)
            acc[mt] = __builtin_amdgcn_mfma_f32_16x16x32_bf16(wf[kc][mt], bfr[kc], acc[mt], 0, 0, 0);

    // D layout: col(n) = lane&15, row(oc) = quad*4 + reg
    #pragma unroll
    for (int mt = 0; mt < 6; ++mt) {
        #pragma unroll
        for (int r = 0; r < 4; ++r) {
            int oc = g * OG_ + mt * 16 + quad * 4 + r;
            float v = acc[mt][r] + bias[oc];
            y[((size_t)b * OUT_ + oc) * N_ + n0 + col] = __float2bfloat16(v);
            float s = v, ss = v * v;
            #pragma unroll
            for (int m = 1; m <= 8; m <<= 1) {
                s  += __shfl_xor(s, m);
                ss += __shfl_xor(ss, m);
            }
            if (col == 0) {
                atomicAdd(&st[oc], s);
                atomicAdd(&st[OUT_ + oc], ss);
            }
        }
    }
}

// ---- Kernel D: BN (batch stats) + exact GELU, write fp32 out [B,OUT,N] ----
__global__ __launch_bounds__(256) void k_bn_gelu(const __hip_bfloat16* __restrict__ y,
                                                 const float* __restrict__ st,
                                                 const float* __restrict__ gamma,
                                                 const float* __restrict__ beta,
                                                 float* __restrict__ out) {
    size_t base = ((size_t)blockIdx.x * 256 + threadIdx.x) * 4;
    int oc = (int)((base / N_) % OUT_);
    const float invM = 1.0f / (float)(B_ * N_);
    float s = st[oc], ss = st[OUT_ + oc];
    float mean = s * invM;
    float var  = ss * invM - mean * mean;
    float inv  = 1.0f / sqrtf(var + 1e-5f);
    float sc = gamma[oc] * inv;
    float sh = beta[oc] - mean * sc;

    const __hip_bfloat162* yp = reinterpret_cast<const __hip_bfloat162*>(y + base);
    __hip_bfloat162 p0 = yp[0], p1 = yp[1];
    float v[4] = { __bfloat162float(p0.x), __bfloat162float(p0.y),
                   __bfloat162float(p1.x), __bfloat162float(p1.y) };
    float4 o;
    float* op = &o.x;
    #pragma unroll
    for (int j = 0; j < 4; ++j) {
        float t = v[j] * sc + sh;
        op[j] = 0.5f * t * (1.0f + erff(t * 0.70710678118654752f));
    }
    *reinterpret_cast<float4*>(out + base) = o;
}

extern "C" void kernel_launch(void* const* d_in, const int* in_sizes, int n_in,
                              void* d_out, int out_size, void* d_ws, size_t ws_size,
                              hipStream_t stream) {
    const float* x      = (const float*)d_in[0];
    const int*   eidx   = (const int*)d_in[1];
    const float* conv_w = (const float*)d_in[2];
    const float* conv_b = (const float*)d_in[3];
    const float* gamma  = (const float*)d_in[4];
    const float* beta   = (const float*)d_in[5];
    float* out = (float*)d_out;

    char* ws = (char*)d_ws;
    __hip_bfloat16* xT = (__hip_bfloat16*)(ws + OFF_XT);
    __hip_bfloat16* xc = (__hip_bfloat16*)(ws + OFF_XC);
    __hip_bfloat16* y  = (__hip_bfloat16*)(ws + OFF_Y);
    float*          st = (float*)(ws + OFF_ST);

    k_transpose<<<dim3(B_, C_ / 64, N_ / 64), 256, 0, stream>>>(x, xT, st);
    k_gather<<<dim3(B_, N_ / 8), 256, 0, stream>>>(xT, eidx, xc);
    k_conv<<<dim3(B_, G_, N_ / 64), 256, 0, stream>>>(xc, conv_w, conv_b, y, st);
    k_bn_gelu<<<dim3((B_ * OUT_ * N_) / (256 * 4)), 256, 0, stream>>>(y, st, gamma, beta, out);
}

// Round 4
// 162.587 us; speedup vs baseline: 2.0211x; 2.0211x over previous
//
#include <hip/hip_runtime.h>
#include <hip/hip_bf16.h>
#include <math.h>

#define B_   8
#define C_   192
#define N_   3136
#define K_   9
#define OUT_ 384
#define G_   4
#define CG_  96   // in-channels per group (2C/G)
#define OG_  96   // out-channels per group
#define NTILES 49 // N_/64

typedef __attribute__((ext_vector_type(8))) short short8;
typedef __attribute__((ext_vector_type(4))) float floatx4;

// ---------------- ws layout (bytes) ----------------
// xT : B*N*C   bf16 =  9,633,792
// xc : B*N*2C  bf16 = 19,267,584
// y  : B*OUT*N bf16 = 19,267,584
// sp : B*G*49*192 f32 = 1,204,224   (per-block BN partials: [0..96)=s, [96..192)=ss)
// st : OUT*2   f32
static const size_t OFF_XT = 0;
static const size_t OFF_XC = 9633792;
static const size_t OFF_Y  = OFF_XC + 19267584;
static const size_t OFF_SP = OFF_Y  + 19267584;
static const size_t OFF_ST = OFF_SP + 1204224;

__device__ inline short f2bs(float f) {
    __hip_bfloat16 h = __float2bfloat16(f);
    union { __hip_bfloat16 h; short s; } u; u.h = h; return u.s;
}
__device__ inline float blo(unsigned int u) {
    unsigned int v = u << 16; return __builtin_bit_cast(float, v);
}
__device__ inline float bhi(unsigned int u) {
    unsigned int v = u & 0xffff0000u; return __builtin_bit_cast(float, v);
}
__device__ inline unsigned int packbf(float lo, float hi) {
    unsigned int l = (unsigned int)(unsigned short)f2bs(lo);
    unsigned int h = (unsigned int)(unsigned short)f2bs(hi);
    return (h << 16) | l;
}

// ---- Kernel A: transpose x [B,C,N] f32 -> xT [B,N,C] bf16 ----
__global__ __launch_bounds__(256) void k_transpose(const float* __restrict__ x,
                                                   __hip_bfloat16* __restrict__ xT) {
    __shared__ float tile[64][65];
    int b  = blockIdx.x;
    int cb = blockIdx.y * 64;
    int nb = blockIdx.z * 64;
    int tid = threadIdx.x;
    int tn  = tid & 63;
    int tc4 = tid >> 6;
    const float* xp = x + ((size_t)b * C_ + cb) * N_ + nb;
    #pragma unroll
    for (int i = 0; i < 16; ++i) {
        int c = tc4 + i * 4;
        tile[c][tn] = xp[(size_t)c * N_ + tn];
    }
    __syncthreads();
    __hip_bfloat16* xo = xT + ((size_t)b * N_ + nb) * C_ + cb;
    int tcl = tid & 63;
    int tn4 = tid >> 6;
    #pragma unroll
    for (int i = 0; i < 16; ++i) {
        int n = tn4 + i * 4;
        xo[(size_t)n * C_ + tcl] = __float2bfloat16(tile[tcl][n]);
    }
}

// ---- Kernel B: LEAN gather + max-relative -> xc [B,N,2C] bf16 ----
// 8 nodes per 256-block (one node per half-wave); dword loads; no LDS.
__global__ __launch_bounds__(256) void k_gather(const __hip_bfloat16* __restrict__ xT,
                                                const int* __restrict__ eidx,
                                                __hip_bfloat16* __restrict__ xc) {
    int b    = blockIdx.x;
    int tid  = threadIdx.x;
    int half = tid >> 5;              // 0..7: node slot within block
    int cd   = tid & 31;              // channel-dword lane
    int n    = blockIdx.y * 8 + half;

    const int* e0 = eidx + ((size_t)b * N_ + n) * K_;                        // x_j idx
    const int* e1 = eidx + (size_t)B_ * N_ * K_ + ((size_t)b * N_ + n) * K_; // x_i idx
    int o0[K_], o1[K_];
    #pragma unroll
    for (int k = 0; k < K_; ++k) { o0[k] = e0[k] * (C_ / 2); o1[k] = e1[k] * (C_ / 2); }

    const unsigned int* xb = reinterpret_cast<const unsigned int*>(xT + (size_t)b * N_ * C_);
    const unsigned int* xn = xb + (size_t)n * (C_ / 2);
    unsigned int* outrow = reinterpret_cast<unsigned int*>(xc) + ((size_t)b * N_ + n) * C_;

    #pragma unroll
    for (int it = 0; it < 3; ++it) {
        int c2 = cd + it * 32;        // dword idx in [0,96): channels 2c2, 2c2+1
        unsigned int ctr = xn[c2];
        float r0 = -INFINITY, r1 = -INFINITY;
        #pragma unroll
        for (int k = 0; k < K_; ++k) {
            unsigned int uj = xb[(size_t)o0[k] + c2];
            unsigned int ui = xb[(size_t)o1[k] + c2];
            r0 = fmaxf(r0, blo(uj) - blo(ui));
            r1 = fmaxf(r1, bhi(uj) - bhi(ui));
        }
        uint2 o;
        o.x = packbf(blo(ctr), r0);   // elems 4c2,4c2+1  : x_{2c2}, rel_{2c2}
        o.y = packbf(bhi(ctr), r1);   // elems 4c2+2,4c2+3: x_{2c2+1}, rel_{2c2+1}
        *reinterpret_cast<uint2*>(outrow + 2 * c2) = o;
    }
}

// ---- Kernel C: grouped 1x1 conv via bf16 MFMA + NON-ATOMIC BN partials ----
__global__ __launch_bounds__(256) void k_conv(const __hip_bfloat16* __restrict__ xc,
                                              const float* __restrict__ conv_w,
                                              const float* __restrict__ bias,
                                              __hip_bfloat16* __restrict__ y,
                                              float* __restrict__ sp) {
    int b  = blockIdx.x;
    int g  = blockIdx.y;
    int nt = blockIdx.z;
    int lane = threadIdx.x & 63;
    int wid  = threadIdx.x >> 6;
    int n0   = nt * 64 + wid * 16;
    int col  = lane & 15;
    int quad = lane >> 4;

    __shared__ float red[4][192];

    // weight fragments: fp32 -> bf16 in-register (L2-resident)
    short8 wf[3][6];
    #pragma unroll
    for (int mt = 0; mt < 6; ++mt) {
        #pragma unroll
        for (int kc = 0; kc < 3; ++kc) {
            const float* wp = conv_w + (size_t)(g * OG_ + mt * 16 + col) * CG_ + kc * 32 + quad * 8;
            float4 w0 = *reinterpret_cast<const float4*>(wp);
            float4 w1 = *reinterpret_cast<const float4*>(wp + 4);
            short8 v;
            v[0] = f2bs(w0.x); v[1] = f2bs(w0.y); v[2] = f2bs(w0.z); v[3] = f2bs(w0.w);
            v[4] = f2bs(w1.x); v[5] = f2bs(w1.y); v[6] = f2bs(w1.z); v[7] = f2bs(w1.w);
            wf[kc][mt] = v;
        }
    }

    const short* Xp = reinterpret_cast<const short*>(xc);
    size_t rowbase = ((size_t)b * N_ + n0 + col) * (2 * C_) + (size_t)g * CG_;
    short8 bfr[3];
    #pragma unroll
    for (int kc = 0; kc < 3; ++kc)
        bfr[kc] = *reinterpret_cast<const short8*>(Xp + rowbase + kc * 32 + quad * 8);

    floatx4 acc[6];
    #pragma unroll
    for (int mt = 0; mt < 6; ++mt) acc[mt] = (floatx4){0.f, 0.f, 0.f, 0.f};
    #pragma unroll
    for (int kc = 0; kc < 3; ++kc)
        #pragma unroll
        for (int mt = 0; mt < 6; ++mt)
            acc[mt] = __builtin_amdgcn_mfma_f32_16x16x32_bf16(wf[kc][mt], bfr[kc], acc[mt], 0, 0, 0);

    // D layout: col(n) = lane&15, row(oc) = quad*4 + reg
    #pragma unroll
    for (int mt = 0; mt < 6; ++mt) {
        #pragma unroll
        for (int r = 0; r < 4; ++r) {
            int ol = mt * 16 + quad * 4 + r;     // oc within group, 0..95
            int oc = g * OG_ + ol;
            float v = acc[mt][r] + bias[oc];
            y[((size_t)b * OUT_ + oc) * N_ + n0 + col] = __float2bfloat16(v);
            float s = v, ss = v * v;
            #pragma unroll
            for (int m = 1; m <= 8; m <<= 1) {
                s  += __shfl_xor(s, m);
                ss += __shfl_xor(ss, m);
            }
            if (col == 0) {
                red[wid][ol]      = s;
                red[wid][96 + ol] = ss;
            }
        }
    }
    __syncthreads();
    int tid = threadIdx.x;
    if (tid < 192) {
        float t = red[0][tid] + red[1][tid] + red[2][tid] + red[3][tid];
        sp[(((size_t)b * G_ + g) * NTILES + nt) * 192 + tid] = t;
    }
}

// ---- Kernel D: fold per-block partials into st[OUT*2] ----
__global__ __launch_bounds__(256) void k_redstats(const float* __restrict__ sp,
                                                  float* __restrict__ st) {
    int oc = blockIdx.x;
    int g  = oc / OG_;
    int o  = oc % OG_;
    float s = 0.f, ss = 0.f;
    for (int e = threadIdx.x; e < B_ * NTILES; e += 256) {
        int b  = e / NTILES;
        int nt = e % NTILES;
        const float* p = sp + (((size_t)b * G_ + g) * NTILES + nt) * 192;
        s  += p[o];
        ss += p[96 + o];
    }
    #pragma unroll
    for (int m = 32; m; m >>= 1) {
        s  += __shfl_xor(s, m);
        ss += __shfl_xor(ss, m);
    }
    __shared__ float ls[4], lss[4];
    int wid = threadIdx.x >> 6, lane = threadIdx.x & 63;
    if (lane == 0) { ls[wid] = s; lss[wid] = ss; }
    __syncthreads();
    if (threadIdx.x == 0) {
        st[oc]        = ls[0] + ls[1] + ls[2] + ls[3];
        st[OUT_ + oc] = lss[0] + lss[1] + lss[2] + lss[3];
    }
}

// ---- Kernel E: BN (batch stats) + exact GELU, write fp32 out [B,OUT,N] ----
__global__ __launch_bounds__(256) void k_bn_gelu(const __hip_bfloat16* __restrict__ y,
                                                 const float* __restrict__ st,
                                                 const float* __restrict__ gamma,
                                                 const float* __restrict__ beta,
                                                 float* __restrict__ out) {
    size_t base = ((size_t)blockIdx.x * 256 + threadIdx.x) * 4;
    int oc = (int)((base / N_) % OUT_);
    const float invM = 1.0f / (float)(B_ * N_);
    float s = st[oc], ss = st[OUT_ + oc];
    float mean = s * invM;
    float var  = ss * invM - mean * mean;
    float inv  = 1.0f / sqrtf(var + 1e-5f);
    float sc = gamma[oc] * inv;
    float sh = beta[oc] - mean * sc;

    const __hip_bfloat162* yp = reinterpret_cast<const __hip_bfloat162*>(y + base);
    __hip_bfloat162 p0 = yp[0], p1 = yp[1];
    float v[4] = { __bfloat162float(p0.x), __bfloat162float(p0.y),
                   __bfloat162float(p1.x), __bfloat162float(p1.y) };
    float4 o;
    float* op = &o.x;
    #pragma unroll
    for (int j = 0; j < 4; ++j) {
        float t = v[j] * sc + sh;
        op[j] = 0.5f * t * (1.0f + erff(t * 0.70710678118654752f));
    }
    *reinterpret_cast<float4*>(out + base) = o;
}

extern "C" void kernel_launch(void* const* d_in, const int* in_sizes, int n_in,
                              void* d_out, int out_size, void* d_ws, size_t ws_size,
                              hipStream_t stream) {
    const float* x      = (const float*)d_in[0];
    const int*   eidx   = (const int*)d_in[1];
    const float* conv_w = (const float*)d_in[2];
    const float* conv_b = (const float*)d_in[3];
    const float* gamma  = (const float*)d_in[4];
    const float* beta   = (const float*)d_in[5];
    float* out = (float*)d_out;

    char* ws = (char*)d_ws;
    __hip_bfloat16* xT = (__hip_bfloat16*)(ws + OFF_XT);
    __hip_bfloat16* xc = (__hip_bfloat16*)(ws + OFF_XC);
    __hip_bfloat16* y  = (__hip_bfloat16*)(ws + OFF_Y);
    float*          sp = (float*)(ws + OFF_SP);
    float*          st = (float*)(ws + OFF_ST);

    k_transpose<<<dim3(B_, C_ / 64, N_ / 64), 256, 0, stream>>>(x, xT);
    k_gather<<<dim3(B_, N_ / 8), 256, 0, stream>>>(xT, eidx, xc);
    k_conv<<<dim3(B_, G_, NTILES), 256, 0, stream>>>(xc, conv_w, conv_b, y, sp);
    k_redstats<<<OUT_, 256, 0, stream>>>(sp, st);
    k_bn_gelu<<<dim3((B_ * OUT_ * N_) / (256 * 4)), 256, 0, stream>>>(y, st, gamma, beta, out);
}

// Round 5
// 136.573 us; speedup vs baseline: 2.4060x; 1.1905x over previous
//
#include <hip/hip_runtime.h>
#include <hip/hip_bf16.h>
#include <math.h>

#define B_   8
#define C_   192
#define N_   3136
#define K_   9
#define OUT_ 384
#define G_   4
#define CG_  96   // in-channels per group (2C/G)
#define OG_  96   // out-channels per group
#define NTILES 49 // N_/64

typedef __attribute__((ext_vector_type(8))) short short8;
typedef __attribute__((ext_vector_type(4))) float floatx4;

// ---------------- ws layout (bytes) ----------------
// xT : B*N*C   bf16 =  9,633,792
// xc : B*N*2C  bf16 = 19,267,584
// y  : B*OUT*N bf16 = 19,267,584
// sp : B*G*49*192 f32 = 1,204,224   (per-block BN partials)
// wb : OUT*CG  bf16 =     73,728
// st : OUT*2   f32
static const size_t OFF_XT = 0;
static const size_t OFF_XC = 9633792;
static const size_t OFF_Y  = OFF_XC + 19267584;
static const size_t OFF_SP = OFF_Y  + 19267584;
static const size_t OFF_WB = OFF_SP + 1204224;
static const size_t OFF_ST = OFF_WB + 73728;

__device__ inline short f2bs(float f) {
    __hip_bfloat16 h = __float2bfloat16(f);
    union { __hip_bfloat16 h; short s; } u; u.h = h; return u.s;
}
__device__ inline float blo(unsigned int u) {
    unsigned int v = u << 16; return __builtin_bit_cast(float, v);
}
__device__ inline float bhi(unsigned int u) {
    unsigned int v = u & 0xffff0000u; return __builtin_bit_cast(float, v);
}
__device__ inline unsigned int packbf(float lo, float hi) {
    unsigned int l = (unsigned int)(unsigned short)f2bs(lo);
    unsigned int h = (unsigned int)(unsigned short)f2bs(hi);
    return (h << 16) | l;
}

// ---- Kernel A: transpose x [B,C,N] f32 -> xT [B,N,C] bf16; fold W->bf16 ----
__global__ __launch_bounds__(256) void k_transpose(const float* __restrict__ x,
                                                   __hip_bfloat16* __restrict__ xT,
                                                   const float* __restrict__ w,
                                                   __hip_bfloat16* __restrict__ wb) {
    // weight conversion folded into 144 of the 392 y==0 blocks (36864 = 144*256)
    if (blockIdx.y == 0) {
        int j = blockIdx.x * NTILES + blockIdx.z;
        if (j < 144) {
            int i = j * 256 + threadIdx.x;
            wb[i] = __float2bfloat16(w[i]);
        }
    }
    __shared__ float tile[64][65];
    int b  = blockIdx.x;
    int cb = blockIdx.y * 64;
    int nb = blockIdx.z * 64;
    int tid = threadIdx.x;
    int tn  = tid & 63;
    int tc4 = tid >> 6;
    const float* xp = x + ((size_t)b * C_ + cb) * N_ + nb;
    #pragma unroll
    for (int i = 0; i < 16; ++i) {
        int c = tc4 + i * 4;
        tile[c][tn] = xp[(size_t)c * N_ + tn];
    }
    __syncthreads();
    __hip_bfloat16* xo = xT + ((size_t)b * N_ + nb) * C_ + cb;
    int tcl = tid & 63;
    int tn4 = tid >> 6;
    #pragma unroll
    for (int i = 0; i < 16; ++i) {
        int n = tn4 + i * 4;
        xo[(size_t)n * C_ + tcl] = __float2bfloat16(tile[tcl][n]);
    }
}

// ---- Kernel B: LEAN gather + max-relative -> xc [B,N,2C] bf16 ----
__global__ __launch_bounds__(256) void k_gather(const __hip_bfloat16* __restrict__ xT,
                                                const int* __restrict__ eidx,
                                                __hip_bfloat16* __restrict__ xc) {
    int b    = blockIdx.x;
    int tid  = threadIdx.x;
    int half = tid >> 5;              // 0..7: node slot within block
    int cd   = tid & 31;              // channel-dword lane
    int n    = blockIdx.y * 8 + half;

    const int* e0 = eidx + ((size_t)b * N_ + n) * K_;                        // x_j idx
    const int* e1 = eidx + (size_t)B_ * N_ * K_ + ((size_t)b * N_ + n) * K_; // x_i idx
    int o0[K_], o1[K_];
    #pragma unroll
    for (int k = 0; k < K_; ++k) { o0[k] = e0[k] * (C_ / 2); o1[k] = e1[k] * (C_ / 2); }

    const unsigned int* xb = reinterpret_cast<const unsigned int*>(xT + (size_t)b * N_ * C_);
    const unsigned int* xn = xb + (size_t)n * (C_ / 2);
    unsigned int* outrow = reinterpret_cast<unsigned int*>(xc) + ((size_t)b * N_ + n) * C_;

    #pragma unroll
    for (int it = 0; it < 3; ++it) {
        int c2 = cd + it * 32;        // dword idx in [0,96): channels 2c2, 2c2+1
        unsigned int ctr = xn[c2];
        float r0 = -INFINITY, r1 = -INFINITY;
        #pragma unroll
        for (int k = 0; k < K_; ++k) {
            unsigned int uj = xb[(size_t)o0[k] + c2];
            unsigned int ui = xb[(size_t)o1[k] + c2];
            r0 = fmaxf(r0, blo(uj) - blo(ui));
            r1 = fmaxf(r1, bhi(uj) - bhi(ui));
        }
        uint2 o;
        o.x = packbf(blo(ctr), r0);
        o.y = packbf(bhi(ctr), r1);
        *reinterpret_cast<uint2*>(outrow + 2 * c2) = o;
    }
}

// ---- Kernel C: grouped 1x1 conv via bf16 MFMA, LDS-staged swizzled weights ----
__global__ __launch_bounds__(256) void k_conv(const __hip_bfloat16* __restrict__ xc,
                                              const __hip_bfloat16* __restrict__ Wb,
                                              const float* __restrict__ bias,
                                              __hip_bfloat16* __restrict__ y,
                                              float* __restrict__ sp) {
    int b  = blockIdx.x;
    int g  = blockIdx.y;
    int nt = blockIdx.z;
    int tid  = threadIdx.x;
    int lane = tid & 63;
    int wid  = tid >> 6;
    int n0   = nt * 64 + wid * 16;
    int col  = lane & 15;
    int quad = lane >> 4;

    __shared__ short wl[OG_ * CG_];   // 18,432 B, fragment-order swizzled
    __shared__ float red[4][192];

    // xc fragment loads (independent of staging; issue early)
    const short* Xp = reinterpret_cast<const short*>(xc);
    size_t rowbase = ((size_t)b * N_ + n0 + col) * (2 * C_) + (size_t)g * CG_;
    short8 bfr[3];
    #pragma unroll
    for (int kc = 0; kc < 3; ++kc)
        bfr[kc] = *reinterpret_cast<const short8*>(Xp + rowbase + kc * 32 + quad * 8);

    // stage group-g weights: coalesced global uint2 reads -> swizzled LDS
    // fragment order: pos = ((((mt*3+kc)*4+quad)*16+col)*8 + j) shorts
    const uint2* src = reinterpret_cast<const uint2*>(Wb + (size_t)g * OG_ * CG_);
    #pragma unroll
    for (int it = 0; it < 9; ++it) {
        int i  = it * 256 + tid;      // uint2 index, 2304 total
        uint2 v = src[i];
        int gs = i * 4;               // short index within group block
        int oc = gs / CG_;
        int cg = gs - oc * CG_;
        int mt = oc >> 4, cl = oc & 15;
        int kc = cg >> 5, rem = cg & 31;
        int qd = rem >> 3, j = rem & 7;   // j in {0,4}
        int pos = (((mt * 3 + kc) * 4 + qd) * 16 + cl) * 8 + j;
        *reinterpret_cast<uint2*>(&wl[pos]) = v;
    }
    __syncthreads();

    floatx4 acc[6];
    #pragma unroll
    for (int mt = 0; mt < 6; ++mt) acc[mt] = (floatx4){0.f, 0.f, 0.f, 0.f};
    #pragma unroll
    for (int kc = 0; kc < 3; ++kc) {
        #pragma unroll
        for (int mt = 0; mt < 6; ++mt) {
            short8 wf = *reinterpret_cast<const short8*>(
                &wl[(((mt * 3 + kc) * 4 + quad) * 16 + col) * 8]);
            acc[mt] = __builtin_amdgcn_mfma_f32_16x16x32_bf16(wf, bfr[kc], acc[mt], 0, 0, 0);
        }
    }

    // D layout: col(n) = lane&15, row(oc) = quad*4 + reg
    #pragma unroll
    for (int mt = 0; mt < 6; ++mt) {
        #pragma unroll
        for (int r = 0; r < 4; ++r) {
            int ol = mt * 16 + quad * 4 + r;     // oc within group, 0..95
            int oc = g * OG_ + ol;
            float v = acc[mt][r] + bias[oc];
            y[((size_t)b * OUT_ + oc) * N_ + n0 + col] = __float2bfloat16(v);
            float s = v, ss = v * v;
            #pragma unroll
            for (int m = 1; m <= 8; m <<= 1) {
                s  += __shfl_xor(s, m);
                ss += __shfl_xor(ss, m);
            }
            if (col == 0) {
                red[wid][ol]      = s;
                red[wid][96 + ol] = ss;
            }
        }
    }
    __syncthreads();
    if (tid < 192) {
        float t = red[0][tid] + red[1][tid] + red[2][tid] + red[3][tid];
        sp[(((size_t)b * G_ + g) * NTILES + nt) * 192 + tid] = t;
    }
}

// ---- Kernel D: fold per-block partials into st[OUT*2] ----
__global__ __launch_bounds__(256) void k_redstats(const float* __restrict__ sp,
                                                  float* __restrict__ st) {
    int oc = blockIdx.x;
    int g  = oc / OG_;
    int o  = oc % OG_;
    float s = 0.f, ss = 0.f;
    for (int e = threadIdx.x; e < B_ * NTILES; e += 256) {
        int b  = e / NTILES;
        int nt = e % NTILES;
        const float* p = sp + (((size_t)b * G_ + g) * NTILES + nt) * 192;
        s  += p[o];
        ss += p[96 + o];
    }
    #pragma unroll
    for (int m = 32; m; m >>= 1) {
        s  += __shfl_xor(s, m);
        ss += __shfl_xor(ss, m);
    }
    __shared__ float ls[4], lss[4];
    int wid = threadIdx.x >> 6, lane = threadIdx.x & 63;
    if (lane == 0) { ls[wid] = s; lss[wid] = ss; }
    __syncthreads();
    if (threadIdx.x == 0) {
        st[oc]        = ls[0] + ls[1] + ls[2] + ls[3];
        st[OUT_ + oc] = lss[0] + lss[1] + lss[2] + lss[3];
    }
}

// ---- Kernel E: BN (batch stats) + exact GELU, write fp32 out [B,OUT,N] ----
__global__ __launch_bounds__(256) void k_bn_gelu(const __hip_bfloat16* __restrict__ y,
                                                 const float* __restrict__ st,
                                                 const float* __restrict__ gamma,
                                                 const float* __restrict__ beta,
                                                 float* __restrict__ out) {
    size_t base = ((size_t)blockIdx.x * 256 + threadIdx.x) * 4;
    int oc = (int)((base / N_) % OUT_);
    const float invM = 1.0f / (float)(B_ * N_);
    float s = st[oc], ss = st[OUT_ + oc];
    float mean = s * invM;
    float var  = ss * invM - mean * mean;
    float inv  = 1.0f / sqrtf(var + 1e-5f);
    float sc = gamma[oc] * inv;
    float sh = beta[oc] - mean * sc;

    const __hip_bfloat162* yp = reinterpret_cast<const __hip_bfloat162*>(y + base);
    __hip_bfloat162 p0 = yp[0], p1 = yp[1];
    float v[4] = { __bfloat162float(p0.x), __bfloat162float(p0.y),
                   __bfloat162float(p1.x), __bfloat162float(p1.y) };
    float4 o;
    float* op = &o.x;
    #pragma unroll
    for (int j = 0; j < 4; ++j) {
        float t = v[j] * sc + sh;
        op[j] = 0.5f * t * (1.0f + erff(t * 0.70710678118654752f));
    }
    *reinterpret_cast<float4*>(out + base) = o;
}

extern "C" void kernel_launch(void* const* d_in, const int* in_sizes, int n_in,
                              void* d_out, int out_size, void* d_ws, size_t ws_size,
                              hipStream_t stream) {
    const float* x      = (const float*)d_in[0];
    const int*   eidx   = (const int*)d_in[1];
    const float* conv_w = (const float*)d_in[2];
    const float* conv_b = (const float*)d_in[3];
    const float* gamma  = (const float*)d_in[4];
    const float* beta   = (const float*)d_in[5];
    float* out = (float*)d_out;

    char* ws = (char*)d_ws;
    __hip_bfloat16* xT = (__hip_bfloat16*)(ws + OFF_XT);
    __hip_bfloat16* xc = (__hip_bfloat16*)(ws + OFF_XC);
    __hip_bfloat16* y  = (__hip_bfloat16*)(ws + OFF_Y);
    float*          sp = (float*)(ws + OFF_SP);
    __hip_bfloat16* wb = (__hip_bfloat16*)(ws + OFF_WB);
    float*          st = (float*)(ws + OFF_ST);

    k_transpose<<<dim3(B_, C_ / 64, N_ / 64), 256, 0, stream>>>(x, xT, conv_w, wb);
    k_gather<<<dim3(B_, N_ / 8), 256, 0, stream>>>(xT, eidx, xc);
    k_conv<<<dim3(B_, G_, NTILES), 256, 0, stream>>>(xc, wb, conv_b, y, sp);
    k_redstats<<<OUT_, 256, 0, stream>>>(sp, st);
    k_bn_gelu<<<dim3((B_ * OUT_ * N_) / (256 * 4)), 256, 0, stream>>>(y, st, gamma, beta, out);
}